// Round 1
// baseline (49875.470 us; speedup 1.0000x reference)
//
#include <hip/hip_runtime.h>
#include <hip/hip_bf16.h>

// ForecastNetSimple: B=128, T=512, I=8, H=512, W=96
// Persistent cooperative-style kernel, 256 blocks x 256 threads, custom grid barrier.
// Block = 4 h-rows x 64 batch cols. Wave = 128-wide k-slice, lane = batch col.
// Whh weights are wave-uniform -> s_load/SGPR broadcast; h in VGPRs.

#define NBLK 256u

// ---------- dtype-flexible load (flag: 1 = inputs are bf16, 0 = fp32) ----------
__device__ __forceinline__ float ldf(const void* p, size_t i, int isbf) {
  if (isbf) return __bfloat162float(((const __hip_bfloat16*)p)[i]);
  return ((const float*)p)[i];
}

// ---------- probe: decide whether input buffers hold bf16 or fp32 ----------
__global__ void k_probe(const unsigned int* __restrict__ src_raw, int* __restrict__ flag) {
  __shared__ int cnt;
  if (threadIdx.x == 0) cnt = 0;
  __syncthreads();
  int c = 0;
  for (int i = threadIdx.x; i < 512; i += 256) {
    unsigned v = src_raw[i];
    float f = __uint_as_float((v & 0xffffu) << 16);  // low 16 bits as bf16
    float a = fabsf(f);
    if (a > 0.00390625f && a < 4.0f) c++;
  }
  atomicAdd(&cnt, c);
  __syncthreads();
  if (threadIdx.x == 0) *flag = (cnt > 256) ? 1 : 0;
}

// ---------- weight gather/convert ----------
// Dest row d = hb*16 + r, r = type*4 + jj  ->  source gate row g = type*512 + hb*4 + jj
__global__ void k_prep_rows(const void* __restrict__ Whh_e, const void* __restrict__ Whh_d,
                            const void* __restrict__ Wih_e, const void* __restrict__ Wih_d,
                            const void* __restrict__ bih_e, const void* __restrict__ bhh_e,
                            const void* __restrict__ bih_d, const void* __restrict__ bhh_d,
                            const void* __restrict__ Wp,    const void* __restrict__ bp,
                            float* __restrict__ WeG, float* __restrict__ WdG,
                            float* __restrict__ WihEG, float* __restrict__ bEG,
                            float* __restrict__ uDG, float* __restrict__ bDG,
                            const int* __restrict__ flag) {
  const int isbf = *flag;
  const int d = blockIdx.x;
  const int hb = d >> 4, r = d & 15, type = r >> 2, jj = r & 3;
  const int g = type * 512 + hb * 4 + jj;
  for (int k = threadIdx.x; k < 512; k += 256) {
    WeG[(size_t)d * 512 + k] = ldf(Whh_e, (size_t)g * 512 + k, isbf);
    WdG[(size_t)d * 512 + k] = ldf(Whh_d, (size_t)g * 512 + k, isbf);
  }
  if (threadIdx.x < 8)
    WihEG[d * 8 + threadIdx.x] = ldf(Wih_e, (size_t)g * 8 + threadIdx.x, isbf);
  if (threadIdx.x == 0) {
    bEG[d] = ldf(bih_e, g, isbf) + ldf(bhh_e, g, isbf);
    float u = 0.f, w0 = 0.f;
    for (int i = 0; i < 8; ++i) {
      float wv = ldf(Wih_d, (size_t)g * 8 + i, isbf);
      u  += wv * ldf(Wp, i, isbf);
      w0 += wv * ldf(bp, i, isbf);
    }
    uDG[d] = u;
    bDG[d] = ldf(bih_d, g, isbf) + ldf(bhh_d, g, isbf) + w0;
  }
}

// ---------- src/Wfc convert + barrier counter reset ----------
__global__ void k_prep_src(const void* __restrict__ src, const void* __restrict__ Wfc,
                           const void* __restrict__ bfc, float* __restrict__ srcF,
                           float* __restrict__ WfcF, unsigned* __restrict__ barcnt,
                           const int* __restrict__ flag) {
  const int isbf = *flag;
  const int b = blockIdx.x;
  if (b < 1024) {
    int i = b * 256 + threadIdx.x;
    srcF[i] = ldf(src, i, isbf);
  } else {
    for (int k = threadIdx.x; k < 512; k += 256) WfcF[k] = ldf(Wfc, k, isbf);
    if (threadIdx.x == 0) { WfcF[512] = ldf(bfc, 0, isbf); *barcnt = 0u; }
  }
}

// ---------- math helpers ----------
__device__ __forceinline__ float sigm(float x) { return 1.0f / (1.0f + __expf(-x)); }
__device__ __forceinline__ float tanh_(float x) {
  float ax = fabsf(x);
  float e = __expf(-2.0f * ax);          // (0,1], no overflow
  float t = (1.0f - e) / (1.0f + e);
  return copysignf(t, x);
}

// ---------- grid barrier (all 256 blocks are resident) ----------
__device__ __forceinline__ void grid_barrier(unsigned* cnt, unsigned target) {
  __threadfence();      // release this thread's h stores (agent scope)
  __syncthreads();
  if (threadIdx.x == 0) {
    __hip_atomic_fetch_add(cnt, 1u, __ATOMIC_ACQ_REL, __HIP_MEMORY_SCOPE_AGENT);
    while (__hip_atomic_load(cnt, __ATOMIC_ACQUIRE, __HIP_MEMORY_SCOPE_AGENT) < target) {
      __builtin_amdgcn_s_sleep(1);
    }
  }
  __syncthreads();
  __threadfence();      // acquire: invalidate caches before reading peers' h
}

// ---------- helpers for the main kernel ----------
__device__ __forceinline__ void load_h(const float* __restrict__ cur, float hreg[128],
                                       int w, int cl) {
#pragma unroll
  for (int q = 0; q < 32; ++q) {
    const float4 v = *(const float4*)(cur + (((size_t)(w * 32 + q)) * 128 + cl) * 4);
    hreg[4 * q + 0] = v.x; hreg[4 * q + 1] = v.y;
    hreg[4 * q + 2] = v.z; hreg[4 * q + 3] = v.w;
  }
}

__device__ __forceinline__ void gemm16(const float* __restrict__ Wg, const float hreg[128],
                                       float part[4][16][64], int hb, int w, int lane) {
  for (int r = 0; r < 16; ++r) {
    const float* wr = Wg + ((size_t)(hb * 16 + r)) * 512 + w * 128;  // wave-uniform -> s_load
    float a0 = 0.f, a1 = 0.f, a2 = 0.f, a3 = 0.f;
#pragma unroll
    for (int k = 0; k < 128; k += 4) {
      a0 = __builtin_fmaf(wr[k + 0], hreg[k + 0], a0);
      a1 = __builtin_fmaf(wr[k + 1], hreg[k + 1], a1);
      a2 = __builtin_fmaf(wr[k + 2], hreg[k + 2], a2);
      a3 = __builtin_fmaf(wr[k + 3], hreg[k + 3], a3);
    }
    part[w][r][lane] = (a0 + a1) + (a2 + a3);
  }
}

// ---------- main persistent recurrent kernel ----------
__global__ __launch_bounds__(256, 2) void k_rnn(
    const float* __restrict__ srcF, const float* __restrict__ WeG,
    const float* __restrict__ WdG, const float* __restrict__ WihEG,
    const float* __restrict__ bEG, const float* __restrict__ uDG,
    const float* __restrict__ bDG, const float* __restrict__ WfcF,
    float* __restrict__ hA, float* __restrict__ hB,
    void* __restrict__ outp, const int* __restrict__ flag,
    unsigned* __restrict__ barcnt) {
  const int hb  = (int)blockIdx.x >> 1;          // h-group: rows hb*4 .. hb*4+3
  const int c0  = ((int)blockIdx.x & 1) << 6;    // batch offset 0 or 64
  const int lane = (int)threadIdx.x & 63;
  const int w   = __builtin_amdgcn_readfirstlane((int)threadIdx.x >> 6);  // k-slice / jj
  const int cl  = c0 + lane;                     // global batch col
  const int jj  = w;                             // combine role: h-row within group

  __shared__ float part[4][16][64];
  __shared__ float predL[64];
  __shared__ float wihL[16][8];
  __shared__ float bEL[16], uDL[16], bDL[16];

  if (threadIdx.x < 128) {
    int r = (int)threadIdx.x >> 3, i = (int)threadIdx.x & 7;
    wihL[r][i] = WihEG[(hb * 16 + r) * 8 + i];
  } else if (threadIdx.x < 144) {
    int r = (int)threadIdx.x - 128;
    bEL[r] = bEG[hb * 16 + r];
    uDL[r] = uDG[hb * 16 + r];
    bDL[r] = bDG[hb * 16 + r];
  }
  const int isbf = *flag;
  __syncthreads();

  float cst = 0.0f;          // c-state for (h-row hb*4+jj, batch cl)
  unsigned round = 1;

  // ================= encoder: 512 steps =================
  for (int t = 0; t < 512; ++t) {
    const float* cur = (t & 1) ? hB : hA;
    float* nxt = (t & 1) ? hA : hB;
    if (t > 0) {
      float hreg[128];
      load_h(cur, hreg, w, cl);
      gemm16(WeG, hreg, part, hb, w, lane);
    } else {
#pragma unroll
      for (int r = 0; r < 16; ++r) part[w][r][lane] = 0.0f;   // h0 = 0
    }
    __syncthreads();
    {
      const float* sp = srcF + ((size_t)cl * 512 + t) * 8;
      float4 xa = *(const float4*)sp;
      float4 xb = *(const float4*)(sp + 4);
      float gate[4];
#pragma unroll
      for (int ty = 0; ty < 4; ++ty) {
        int r = ty * 4 + jj;
        float s = part[0][r][lane] + part[1][r][lane] + part[2][r][lane] + part[3][r][lane];
        s += bEL[r];
        s += wihL[r][0] * xa.x + wihL[r][1] * xa.y + wihL[r][2] * xa.z + wihL[r][3] * xa.w;
        s += wihL[r][4] * xb.x + wihL[r][5] * xb.y + wihL[r][6] * xb.z + wihL[r][7] * xb.w;
        gate[ty] = s;
      }
      float ig = sigm(gate[0]), fg = sigm(gate[1]);
      float gg = tanh_(gate[2]), og = sigm(gate[3]);
      cst = fg * cst + ig * gg;
      float hn = og * tanh_(cst);
      nxt[((size_t)(hb * 128 + cl)) * 4 + jj] = hn;
    }
    grid_barrier(barcnt, (round++) * NBLK);
  }

  // ================= decoder: 96 steps =================
  for (int d = 0; d < 96; ++d) {
    const float* cur = (d & 1) ? hB : hA;
    float* nxt = (d & 1) ? hA : hB;
    float hreg[128];
    load_h(cur, hreg, w, cl);
    // pred_{d-1} = sigmoid(h_d . Wfc + bfc), per-block for its 64 cols
    {
      float p0 = 0.f, p1 = 0.f, p2 = 0.f, p3 = 0.f;
      const float* wf = WfcF + w * 128;   // wave-uniform
#pragma unroll
      for (int k = 0; k < 128; k += 4) {
        p0 = __builtin_fmaf(wf[k + 0], hreg[k + 0], p0);
        p1 = __builtin_fmaf(wf[k + 1], hreg[k + 1], p1);
        p2 = __builtin_fmaf(wf[k + 2], hreg[k + 2], p2);
        p3 = __builtin_fmaf(wf[k + 3], hreg[k + 3], p3);
      }
      part[w][0][lane] = (p0 + p1) + (p2 + p3);
    }
    __syncthreads();
    if (threadIdx.x < 64) {
      float s = part[0][0][lane] + part[1][0][lane] + part[2][0][lane] + part[3][0][lane];
      predL[lane] = sigm(s + WfcF[512]);
    }
    __syncthreads();
    float xin = (d == 0) ? srcF[(size_t)cl * 4096 + 4088] : predL[lane];  // src[b][511][0]
    if (d > 0 && hb == 0 && jj == 0) {
      int oi = cl * 96 + (d - 1);
      if (isbf) ((__hip_bfloat16*)outp)[oi] = __float2bfloat16(predL[lane]);
      else      ((float*)outp)[oi] = predL[lane];
    }
    gemm16(WdG, hreg, part, hb, w, lane);
    __syncthreads();
    {
      float gate[4];
#pragma unroll
      for (int ty = 0; ty < 4; ++ty) {
        int r = ty * 4 + jj;
        float s = part[0][r][lane] + part[1][r][lane] + part[2][r][lane] + part[3][r][lane];
        s += xin * uDL[r] + bDL[r];
        gate[ty] = s;
      }
      float ig = sigm(gate[0]), fg = sigm(gate[1]);
      float gg = tanh_(gate[2]), og = sigm(gate[3]);
      cst = fg * cst + ig * gg;
      float hn = og * tanh_(cst);
      nxt[((size_t)(hb * 128 + cl)) * 4 + jj] = hn;
    }
    grid_barrier(barcnt, (round++) * NBLK);
  }

  // ================= epilogue: pred_95 from h_96 (in hA) =================
  if (hb == 0) {
    float hreg[128];
    load_h(hA, hreg, w, cl);
    float p0 = 0.f, p1 = 0.f, p2 = 0.f, p3 = 0.f;
    const float* wf = WfcF + w * 128;
#pragma unroll
    for (int k = 0; k < 128; k += 4) {
      p0 = __builtin_fmaf(wf[k + 0], hreg[k + 0], p0);
      p1 = __builtin_fmaf(wf[k + 1], hreg[k + 1], p1);
      p2 = __builtin_fmaf(wf[k + 2], hreg[k + 2], p2);
      p3 = __builtin_fmaf(wf[k + 3], hreg[k + 3], p3);
    }
    part[w][0][lane] = (p0 + p1) + (p2 + p3);
    __syncthreads();
    if (threadIdx.x < 64) {
      float s = part[0][0][lane] + part[1][0][lane] + part[2][0][lane] + part[3][0][lane];
      float p = sigm(s + WfcF[512]);
      int oi = cl * 96 + 95;
      if (isbf) ((__hip_bfloat16*)outp)[oi] = __float2bfloat16(p);
      else      ((float*)outp)[oi] = p;
    }
  }
}

// ---------- host ----------
extern "C" void kernel_launch(void* const* d_in, const int* in_sizes, int n_in,
                              void* d_out, int out_size, void* d_ws, size_t ws_size,
                              hipStream_t stream) {
  (void)in_sizes; (void)n_in; (void)out_size; (void)ws_size;
  char* ws = (char*)d_ws;
  int* flag = (int*)ws;
  unsigned* barcnt = (unsigned*)(ws + 8);
  float* f = (float*)(ws + 64);
  float* srcF  = f;                         // 128*512*8   = 524288
  float* WeG   = srcF + 524288;             // 2048*512    = 1048576
  float* WdG   = WeG + 1048576;             // 1048576
  float* WihEG = WdG + 1048576;             // 2048*8      = 16384
  float* bEG   = WihEG + 16384;             // 2048
  float* uDG   = bEG + 2048;                // 2048
  float* bDG   = uDG + 2048;                // 2048
  float* WfcF  = bDG + 2048;                // 513 (pad to 520)
  float* hA    = WfcF + 520;                // 128*128*4   = 65536
  float* hB    = hA + 65536;                // 65536

  // inputs (setup_inputs order):
  // 0 src, 1 Wih_e, 2 Whh_e, 3 bih_e, 4 bhh_e, 5 Wih_d, 6 Whh_d, 7 bih_d, 8 bhh_d,
  // 9 Wp, 10 bp, 11 Wfc, 12 bfc
  k_probe<<<dim3(1), dim3(256), 0, stream>>>((const unsigned int*)d_in[0], flag);
  k_prep_rows<<<dim3(2048), dim3(256), 0, stream>>>(
      d_in[2], d_in[6], d_in[1], d_in[5], d_in[3], d_in[4], d_in[7], d_in[8],
      d_in[9], d_in[10], WeG, WdG, WihEG, bEG, uDG, bDG, flag);
  k_prep_src<<<dim3(1025), dim3(256), 0, stream>>>(
      d_in[0], d_in[11], d_in[12], srcF, WfcF, barcnt, flag);
  k_rnn<<<dim3(256), dim3(256), 0, stream>>>(
      srcF, WeG, WdG, WihEG, bEG, uDG, bDG, WfcF, hA, hB, d_out, flag, barcnt);
}

// Round 2
// 12444.298 us; speedup vs baseline: 4.0079x; 4.0079x over previous
//
#include <hip/hip_runtime.h>
#include <hip/hip_bf16.h>

// ForecastNetSimple: B=128, T=512, I=8, H=512, W=96
// Persistent kernel, 256 blocks x 256 threads, fine-grained-coherent grid barrier.
// Cross-block data (h, flags) uses relaxed AGENT-scope atomics (sc0/sc1 -> L3
// coherence point), so NO threadfence / L2 invalidation anywhere -> weights
// stay L2-resident across all 608 steps.

#define NBLK 256u
#define FLAG_STRIDE 32  // dwords (128 B) between per-block arrival flags

// ---------- dtype-flexible load (flag: 1 = inputs are bf16, 0 = fp32) ----------
__device__ __forceinline__ float ldf(const void* p, size_t i, int isbf) {
  if (isbf) return __bfloat162float(((const __hip_bfloat16*)p)[i]);
  return ((const float*)p)[i];
}

// ---------- coherent helpers (bypass L1/L2, serve at device coherence point) ----------
__device__ __forceinline__ unsigned ld_flag(const unsigned* p) {
  return __hip_atomic_load(p, __ATOMIC_RELAXED, __HIP_MEMORY_SCOPE_AGENT);
}
__device__ __forceinline__ void st_flag(unsigned* p, unsigned v) {
  __hip_atomic_store(p, v, __ATOMIC_RELAXED, __HIP_MEMORY_SCOPE_AGENT);
}
__device__ __forceinline__ unsigned long long ld_h64(const unsigned long long* p) {
  return __hip_atomic_load(p, __ATOMIC_RELAXED, __HIP_MEMORY_SCOPE_AGENT);
}
__device__ __forceinline__ void st_h32(unsigned* p, unsigned v) {
  __hip_atomic_store(p, v, __ATOMIC_RELAXED, __HIP_MEMORY_SCOPE_AGENT);
}

// ---------- probe: decide whether input buffers hold bf16 or fp32 ----------
__global__ void k_probe(const unsigned int* __restrict__ src_raw, int* __restrict__ flag) {
  __shared__ int cnt;
  if (threadIdx.x == 0) cnt = 0;
  __syncthreads();
  int c = 0;
  for (int i = threadIdx.x; i < 512; i += 256) {
    unsigned v = src_raw[i];
    float f = __uint_as_float((v & 0xffffu) << 16);  // low 16 bits as bf16
    float a = fabsf(f);
    if (a > 0.00390625f && a < 4.0f) c++;
  }
  atomicAdd(&cnt, c);
  __syncthreads();
  if (threadIdx.x == 0) *flag = (cnt > 256) ? 1 : 0;
}

// ---------- weight gather/convert ----------
// Dest row d = hb*16 + r, r = type*4 + jj  ->  source gate row g = type*512 + hb*4 + jj
__global__ void k_prep_rows(const void* __restrict__ Whh_e, const void* __restrict__ Whh_d,
                            const void* __restrict__ Wih_e, const void* __restrict__ Wih_d,
                            const void* __restrict__ bih_e, const void* __restrict__ bhh_e,
                            const void* __restrict__ bih_d, const void* __restrict__ bhh_d,
                            const void* __restrict__ Wp,    const void* __restrict__ bp,
                            float* __restrict__ WeG, float* __restrict__ WdG,
                            float* __restrict__ WihEG, float* __restrict__ bEG,
                            float* __restrict__ uDG, float* __restrict__ bDG,
                            const int* __restrict__ flag) {
  const int isbf = *flag;
  const int d = blockIdx.x;
  const int hb = d >> 4, r = d & 15, type = r >> 2, jj = r & 3;
  const int g = type * 512 + hb * 4 + jj;
  for (int k = threadIdx.x; k < 512; k += 256) {
    WeG[(size_t)d * 512 + k] = ldf(Whh_e, (size_t)g * 512 + k, isbf);
    WdG[(size_t)d * 512 + k] = ldf(Whh_d, (size_t)g * 512 + k, isbf);
  }
  if (threadIdx.x < 8)
    WihEG[d * 8 + threadIdx.x] = ldf(Wih_e, (size_t)g * 8 + threadIdx.x, isbf);
  if (threadIdx.x == 0) {
    bEG[d] = ldf(bih_e, g, isbf) + ldf(bhh_e, g, isbf);
    float u = 0.f, w0 = 0.f;
    for (int i = 0; i < 8; ++i) {
      float wv = ldf(Wih_d, (size_t)g * 8 + i, isbf);
      u  += wv * ldf(Wp, i, isbf);
      w0 += wv * ldf(bp, i, isbf);
    }
    uDG[d] = u;
    bDG[d] = ldf(bih_d, g, isbf) + ldf(bhh_d, g, isbf) + w0;
  }
}

// ---------- src/Wfc convert + barrier flag init ----------
__global__ void k_prep_src(const void* __restrict__ src, const void* __restrict__ Wfc,
                           const void* __restrict__ bfc, float* __restrict__ srcF,
                           float* __restrict__ WfcF, unsigned* __restrict__ arr,
                           unsigned* __restrict__ rel, const int* __restrict__ flag) {
  const int isbf = *flag;
  const int b = blockIdx.x;
  if (b < 1024) {
    int i = b * 256 + threadIdx.x;
    srcF[i] = ldf(src, i, isbf);
  } else if (b == 1024) {
    for (int k = threadIdx.x; k < 512; k += 256) WfcF[k] = ldf(Wfc, k, isbf);
    if (threadIdx.x == 0) WfcF[512] = ldf(bfc, 0, isbf);
  } else {
    // zero all barrier state (ws is poisoned 0xAA before every launch)
    for (int k = threadIdx.x; k < 256 * FLAG_STRIDE; k += 256) arr[k] = 0u;
    if (threadIdx.x == 0) *rel = 0u;
  }
}

// ---------- math helpers ----------
__device__ __forceinline__ float sigm(float x) { return 1.0f / (1.0f + __expf(-x)); }
__device__ __forceinline__ float tanh_(float x) {
  float ax = fabsf(x);
  float e = __expf(-2.0f * ax);          // (0,1], no overflow
  float t = (1.0f - e) / (1.0f + e);
  return copysignf(t, x);
}

// ---------- grid barrier: flags on distinct lines, block 0 scans, one release word ----------
__device__ __forceinline__ void grid_barrier(unsigned* arr, unsigned* rel,
                                             unsigned step, int bid) {
  asm volatile("s_waitcnt vmcnt(0)" ::: "memory");  // h stores visible at L3
  __syncthreads();                                   // whole block done storing
  if (bid == 0) {
    if (threadIdx.x == 0) st_flag(&arr[0], step);
    // each of the 256 threads polls one block's arrival flag (distinct lines)
    while (ld_flag(&arr[(int)threadIdx.x * FLAG_STRIDE]) < step)
      __builtin_amdgcn_s_sleep(1);
    __syncthreads();
    if (threadIdx.x == 0) st_flag(rel, step);
  } else {
    if (threadIdx.x == 0) {
      st_flag(&arr[bid * FLAG_STRIDE], step);
      while (ld_flag(rel) < step) __builtin_amdgcn_s_sleep(1);
    }
    __syncthreads();
  }
}

// ---------- coherent h load: 128 floats (k = w*128 .. w*128+127) for batch col cl ----------
__device__ __forceinline__ void load_h(const float* __restrict__ cur, float hreg[128],
                                       int w, int cl) {
  const unsigned long long* p = (const unsigned long long*)cur;
#pragma unroll
  for (int q = 0; q < 32; ++q) {
    size_t base = (((size_t)(w * 32 + q)) * 128 + cl) * 2;  // in 8-byte units
    unsigned long long a = ld_h64(p + base);
    unsigned long long b = ld_h64(p + base + 1);
    hreg[4 * q + 0] = __uint_as_float((unsigned)a);
    hreg[4 * q + 1] = __uint_as_float((unsigned)(a >> 32));
    hreg[4 * q + 2] = __uint_as_float((unsigned)b);
    hreg[4 * q + 3] = __uint_as_float((unsigned)(b >> 32));
  }
}

__device__ __forceinline__ void gemm16(const float* __restrict__ Wg, const float hreg[128],
                                       float part[4][16][64], int hb, int w, int lane) {
  for (int r = 0; r < 16; ++r) {
    const float* wr = Wg + ((size_t)(hb * 16 + r)) * 512 + w * 128;  // wave-uniform -> s_load
    float a0 = 0.f, a1 = 0.f, a2 = 0.f, a3 = 0.f;
#pragma unroll
    for (int k = 0; k < 128; k += 4) {
      a0 = __builtin_fmaf(wr[k + 0], hreg[k + 0], a0);
      a1 = __builtin_fmaf(wr[k + 1], hreg[k + 1], a1);
      a2 = __builtin_fmaf(wr[k + 2], hreg[k + 2], a2);
      a3 = __builtin_fmaf(wr[k + 3], hreg[k + 3], a3);
    }
    part[w][r][lane] = (a0 + a1) + (a2 + a3);
  }
}

// ---------- main persistent recurrent kernel ----------
__global__ __launch_bounds__(256, 2) void k_rnn(
    const float* __restrict__ srcF, const float* __restrict__ WeG,
    const float* __restrict__ WdG, const float* __restrict__ WihEG,
    const float* __restrict__ bEG, const float* __restrict__ uDG,
    const float* __restrict__ bDG, const float* __restrict__ WfcF,
    float* __restrict__ hA, float* __restrict__ hB,
    void* __restrict__ outp, const int* __restrict__ flag,
    unsigned* __restrict__ arr, unsigned* __restrict__ rel) {
  const int bid = (int)blockIdx.x;
  const int hb  = bid >> 1;                      // h-group: gate rows hb*16 .. hb*16+15
  const int c0  = (bid & 1) << 6;                // batch offset 0 or 64
  const int lane = (int)threadIdx.x & 63;
  const int w   = __builtin_amdgcn_readfirstlane((int)threadIdx.x >> 6);  // k-slice / jj
  const int cl  = c0 + lane;                     // global batch col
  const int jj  = w;                             // h-row within group

  __shared__ float part[4][16][64];
  __shared__ float predL[64];
  __shared__ float wihL[16][8];
  __shared__ float bEL[16], uDL[16], bDL[16];

  if (threadIdx.x < 128) {
    int r = (int)threadIdx.x >> 3, i = (int)threadIdx.x & 7;
    wihL[r][i] = WihEG[(hb * 16 + r) * 8 + i];
  } else if (threadIdx.x < 144) {
    int r = (int)threadIdx.x - 128;
    bEL[r] = bEG[hb * 16 + r];
    uDL[r] = uDG[hb * 16 + r];
    bDL[r] = bDG[hb * 16 + r];
  }
  const int isbf = *flag;
  __syncthreads();

  float cst = 0.0f;          // c-state for (h-row hb*4+jj, batch cl)
  unsigned round = 1;

  // ================= encoder: 512 steps =================
  for (int t = 0; t < 512; ++t) {
    const float* cur = (t & 1) ? hB : hA;
    float* nxt = (t & 1) ? hA : hB;
    if (t > 0) {
      float hreg[128];
      load_h(cur, hreg, w, cl);
      gemm16(WeG, hreg, part, hb, w, lane);
    } else {
#pragma unroll
      for (int r = 0; r < 16; ++r) part[w][r][lane] = 0.0f;   // h0 = 0
    }
    __syncthreads();
    {
      const float* sp = srcF + ((size_t)cl * 512 + t) * 8;
      float4 xa = *(const float4*)sp;
      float4 xb = *(const float4*)(sp + 4);
      float gate[4];
#pragma unroll
      for (int ty = 0; ty < 4; ++ty) {
        int r = ty * 4 + jj;
        float s = part[0][r][lane] + part[1][r][lane] + part[2][r][lane] + part[3][r][lane];
        s += bEL[r];
        s += wihL[r][0] * xa.x + wihL[r][1] * xa.y + wihL[r][2] * xa.z + wihL[r][3] * xa.w;
        s += wihL[r][4] * xb.x + wihL[r][5] * xb.y + wihL[r][6] * xb.z + wihL[r][7] * xb.w;
        gate[ty] = s;
      }
      float ig = sigm(gate[0]), fg = sigm(gate[1]);
      float gg = tanh_(gate[2]), og = sigm(gate[3]);
      cst = fg * cst + ig * gg;
      float hn = og * tanh_(cst);
      st_h32((unsigned*)&nxt[((size_t)(hb * 128 + cl)) * 4 + jj], __float_as_uint(hn));
    }
    grid_barrier(arr, rel, round++, bid);
  }

  // ================= decoder: 96 steps =================
  for (int d = 0; d < 96; ++d) {
    const float* cur = (d & 1) ? hB : hA;
    float* nxt = (d & 1) ? hA : hB;
    float hreg[128];
    load_h(cur, hreg, w, cl);
    // pred_{d-1} = sigmoid(h_d . Wfc + bfc), per-block for its 64 cols
    {
      float p0 = 0.f, p1 = 0.f, p2 = 0.f, p3 = 0.f;
      const float* wf = WfcF + w * 128;   // wave-uniform
#pragma unroll
      for (int k = 0; k < 128; k += 4) {
        p0 = __builtin_fmaf(wf[k + 0], hreg[k + 0], p0);
        p1 = __builtin_fmaf(wf[k + 1], hreg[k + 1], p1);
        p2 = __builtin_fmaf(wf[k + 2], hreg[k + 2], p2);
        p3 = __builtin_fmaf(wf[k + 3], hreg[k + 3], p3);
      }
      part[w][0][lane] = (p0 + p1) + (p2 + p3);
    }
    __syncthreads();
    if (threadIdx.x < 64) {
      float s = part[0][0][lane] + part[1][0][lane] + part[2][0][lane] + part[3][0][lane];
      predL[lane] = sigm(s + WfcF[512]);
    }
    __syncthreads();
    float xin = (d == 0) ? srcF[(size_t)cl * 4096 + 4088] : predL[lane];  // src[b][511][0]
    if (d > 0 && hb == 0 && jj == 0) {
      int oi = cl * 96 + (d - 1);
      if (isbf) ((__hip_bfloat16*)outp)[oi] = __float2bfloat16(predL[lane]);
      else      ((float*)outp)[oi] = predL[lane];
    }
    gemm16(WdG, hreg, part, hb, w, lane);
    __syncthreads();
    {
      float gate[4];
#pragma unroll
      for (int ty = 0; ty < 4; ++ty) {
        int r = ty * 4 + jj;
        float s = part[0][r][lane] + part[1][r][lane] + part[2][r][lane] + part[3][r][lane];
        s += xin * uDL[r] + bDL[r];
        gate[ty] = s;
      }
      float ig = sigm(gate[0]), fg = sigm(gate[1]);
      float gg = tanh_(gate[2]), og = sigm(gate[3]);
      cst = fg * cst + ig * gg;
      float hn = og * tanh_(cst);
      st_h32((unsigned*)&nxt[((size_t)(hb * 128 + cl)) * 4 + jj], __float_as_uint(hn));
    }
    grid_barrier(arr, rel, round++, bid);
  }

  // ================= epilogue: pred_95 from h_96 (in hA) =================
  if (hb == 0) {
    float hreg[128];
    load_h(hA, hreg, w, cl);
    float p0 = 0.f, p1 = 0.f, p2 = 0.f, p3 = 0.f;
    const float* wf = WfcF + w * 128;
#pragma unroll
    for (int k = 0; k < 128; k += 4) {
      p0 = __builtin_fmaf(wf[k + 0], hreg[k + 0], p0);
      p1 = __builtin_fmaf(wf[k + 1], hreg[k + 1], p1);
      p2 = __builtin_fmaf(wf[k + 2], hreg[k + 2], p2);
      p3 = __builtin_fmaf(wf[k + 3], hreg[k + 3], p3);
    }
    part[w][0][lane] = (p0 + p1) + (p2 + p3);
    __syncthreads();
    if (threadIdx.x < 64) {
      float s = part[0][0][lane] + part[1][0][lane] + part[2][0][lane] + part[3][0][lane];
      float p = sigm(s + WfcF[512]);
      int oi = cl * 96 + 95;
      if (isbf) ((__hip_bfloat16*)outp)[oi] = __float2bfloat16(p);
      else      ((float*)outp)[oi] = p;
    }
  }
}

// ---------- host ----------
extern "C" void kernel_launch(void* const* d_in, const int* in_sizes, int n_in,
                              void* d_out, int out_size, void* d_ws, size_t ws_size,
                              hipStream_t stream) {
  (void)in_sizes; (void)n_in; (void)out_size; (void)ws_size;
  char* ws = (char*)d_ws;
  int* flag = (int*)ws;
  unsigned* arr = (unsigned*)(ws + 128);                 // 256 flags x 128 B = 32 KB
  unsigned* rel = (unsigned*)(ws + 128 + 32768);
  float* f = (float*)(ws + 128 + 32768 + 128);
  float* srcF  = f;                         // 128*512*8   = 524288
  float* WeG   = srcF + 524288;             // 2048*512    = 1048576
  float* WdG   = WeG + 1048576;             // 1048576
  float* WihEG = WdG + 1048576;             // 2048*8      = 16384
  float* bEG   = WihEG + 16384;             // 2048
  float* uDG   = bEG + 2048;                // 2048
  float* bDG   = uDG + 2048;                // 2048
  float* WfcF  = bDG + 2048;                // 513 (pad to 520)
  float* hA    = WfcF + 520;                // 128*128*4   = 65536
  float* hB    = hA + 65536;                // 65536

  // inputs (setup_inputs order):
  // 0 src, 1 Wih_e, 2 Whh_e, 3 bih_e, 4 bhh_e, 5 Wih_d, 6 Whh_d, 7 bih_d, 8 bhh_d,
  // 9 Wp, 10 bp, 11 Wfc, 12 bfc
  k_probe<<<dim3(1), dim3(256), 0, stream>>>((const unsigned int*)d_in[0], flag);
  k_prep_rows<<<dim3(2048), dim3(256), 0, stream>>>(
      d_in[2], d_in[6], d_in[1], d_in[5], d_in[3], d_in[4], d_in[7], d_in[8],
      d_in[9], d_in[10], WeG, WdG, WihEG, bEG, uDG, bDG, flag);
  k_prep_src<<<dim3(1026), dim3(256), 0, stream>>>(
      d_in[0], d_in[11], d_in[12], srcF, WfcF, arr, rel, flag);
  k_rnn<<<dim3(256), dim3(256), 0, stream>>>(
      srcF, WeG, WdG, WihEG, bEG, uDG, bDG, WfcF, hA, hB, d_out, flag, arr, rel);
}

// Round 3
// 10145.753 us; speedup vs baseline: 4.9159x; 1.2266x over previous
//
#include <hip/hip_runtime.h>
#include <hip/hip_bf16.h>

// ForecastNetSimple: B=128, T=512, I=8, H=512, W=96
// Persistent kernel, 256 blocks x 256 threads (1 block/CU), fine-grained-coherent
// grid barrier. Cross-block data (h, flags) uses relaxed AGENT-scope atomics
// (bypass stale L1/L2, serve at the device coherence point). No threadfence ->
// weights stay L2-resident. Round 3: launch_bounds(256,1) so hreg[128] fits in
// VGPRs without spill; load_h issues all 64 coherent loads BEFORE any use so
// they pipeline behind a single vmcnt drain.

#define NBLK 256u
#define FLAG_STRIDE 32  // dwords (128 B) between per-block arrival flags

// ---------- dtype-flexible load (flag: 1 = inputs are bf16, 0 = fp32) ----------
__device__ __forceinline__ float ldf(const void* p, size_t i, int isbf) {
  if (isbf) return __bfloat162float(((const __hip_bfloat16*)p)[i]);
  return ((const float*)p)[i];
}

// ---------- coherent helpers (bypass L1/L2, serve at device coherence point) ----------
__device__ __forceinline__ unsigned ld_flag(const unsigned* p) {
  return __hip_atomic_load(p, __ATOMIC_RELAXED, __HIP_MEMORY_SCOPE_AGENT);
}
__device__ __forceinline__ void st_flag(unsigned* p, unsigned v) {
  __hip_atomic_store(p, v, __ATOMIC_RELAXED, __HIP_MEMORY_SCOPE_AGENT);
}
__device__ __forceinline__ unsigned long long ld_h64(const unsigned long long* p) {
  return __hip_atomic_load(p, __ATOMIC_RELAXED, __HIP_MEMORY_SCOPE_AGENT);
}
__device__ __forceinline__ void st_h32(unsigned* p, unsigned v) {
  __hip_atomic_store(p, v, __ATOMIC_RELAXED, __HIP_MEMORY_SCOPE_AGENT);
}

// ---------- probe: decide whether input buffers hold bf16 or fp32 ----------
__global__ void k_probe(const unsigned int* __restrict__ src_raw, int* __restrict__ flag) {
  __shared__ int cnt;
  if (threadIdx.x == 0) cnt = 0;
  __syncthreads();
  int c = 0;
  for (int i = threadIdx.x; i < 512; i += 256) {
    unsigned v = src_raw[i];
    float f = __uint_as_float((v & 0xffffu) << 16);  // low 16 bits as bf16
    float a = fabsf(f);
    if (a > 0.00390625f && a < 4.0f) c++;
  }
  atomicAdd(&cnt, c);
  __syncthreads();
  if (threadIdx.x == 0) *flag = (cnt > 256) ? 1 : 0;
}

// ---------- weight gather/convert ----------
// Dest row d = hb*16 + r, r = type*4 + jj  ->  source gate row g = type*512 + hb*4 + jj
__global__ void k_prep_rows(const void* __restrict__ Whh_e, const void* __restrict__ Whh_d,
                            const void* __restrict__ Wih_e, const void* __restrict__ Wih_d,
                            const void* __restrict__ bih_e, const void* __restrict__ bhh_e,
                            const void* __restrict__ bih_d, const void* __restrict__ bhh_d,
                            const void* __restrict__ Wp,    const void* __restrict__ bp,
                            float* __restrict__ WeG, float* __restrict__ WdG,
                            float* __restrict__ WihEG, float* __restrict__ bEG,
                            float* __restrict__ uDG, float* __restrict__ bDG,
                            const int* __restrict__ flag) {
  const int isbf = *flag;
  const int d = blockIdx.x;
  const int hb = d >> 4, r = d & 15, type = r >> 2, jj = r & 3;
  const int g = type * 512 + hb * 4 + jj;
  for (int k = threadIdx.x; k < 512; k += 256) {
    WeG[(size_t)d * 512 + k] = ldf(Whh_e, (size_t)g * 512 + k, isbf);
    WdG[(size_t)d * 512 + k] = ldf(Whh_d, (size_t)g * 512 + k, isbf);
  }
  if (threadIdx.x < 8)
    WihEG[d * 8 + threadIdx.x] = ldf(Wih_e, (size_t)g * 8 + threadIdx.x, isbf);
  if (threadIdx.x == 0) {
    bEG[d] = ldf(bih_e, g, isbf) + ldf(bhh_e, g, isbf);
    float u = 0.f, w0 = 0.f;
    for (int i = 0; i < 8; ++i) {
      float wv = ldf(Wih_d, (size_t)g * 8 + i, isbf);
      u  += wv * ldf(Wp, i, isbf);
      w0 += wv * ldf(bp, i, isbf);
    }
    uDG[d] = u;
    bDG[d] = ldf(bih_d, g, isbf) + ldf(bhh_d, g, isbf) + w0;
  }
}

// ---------- src/Wfc convert + barrier flag init ----------
__global__ void k_prep_src(const void* __restrict__ src, const void* __restrict__ Wfc,
                           const void* __restrict__ bfc, float* __restrict__ srcF,
                           float* __restrict__ WfcF, unsigned* __restrict__ arr,
                           unsigned* __restrict__ rel, const int* __restrict__ flag) {
  const int isbf = *flag;
  const int b = blockIdx.x;
  if (b < 1024) {
    int i = b * 256 + threadIdx.x;
    srcF[i] = ldf(src, i, isbf);
  } else if (b == 1024) {
    for (int k = threadIdx.x; k < 512; k += 256) WfcF[k] = ldf(Wfc, k, isbf);
    if (threadIdx.x == 0) WfcF[512] = ldf(bfc, 0, isbf);
  } else {
    // zero all barrier state (ws is poisoned 0xAA before every launch)
    for (int k = threadIdx.x; k < 256 * FLAG_STRIDE; k += 256) arr[k] = 0u;
    if (threadIdx.x == 0) *rel = 0u;
  }
}

// ---------- math helpers ----------
__device__ __forceinline__ float sigm(float x) { return 1.0f / (1.0f + __expf(-x)); }
__device__ __forceinline__ float tanh_(float x) {
  float ax = fabsf(x);
  float e = __expf(-2.0f * ax);          // (0,1], no overflow
  float t = (1.0f - e) / (1.0f + e);
  return copysignf(t, x);
}

// ---------- grid barrier: flags on distinct lines, block 0 scans, one release word ----------
__device__ __forceinline__ void grid_barrier(unsigned* arr, unsigned* rel,
                                             unsigned step, int bid) {
  asm volatile("s_waitcnt vmcnt(0)" ::: "memory");  // h stores visible at L3
  __syncthreads();                                   // whole block done storing
  if (bid == 0) {
    if (threadIdx.x == 0) st_flag(&arr[0], step);
    // each of the 256 threads polls one block's arrival flag (distinct lines)
    while (ld_flag(&arr[(int)threadIdx.x * FLAG_STRIDE]) < step)
      __builtin_amdgcn_s_sleep(1);
    __syncthreads();
    if (threadIdx.x == 0) st_flag(rel, step);
  } else {
    if (threadIdx.x == 0) {
      st_flag(&arr[bid * FLAG_STRIDE], step);
      while (ld_flag(rel) < step) __builtin_amdgcn_s_sleep(1);
    }
    __syncthreads();
  }
}

// ---------- coherent h load: 128 floats (k = w*128 .. w*128+127) for batch col cl ----------
// Phase 1 issues ALL 64 relaxed atomic loads (no uses), phase 2 converts.
// -> loads pipeline behind a single vmcnt drain instead of waiting per-load.
__device__ __forceinline__ void load_h(const float* __restrict__ cur, float hreg[128],
                                       int w, int cl) {
  const unsigned long long* p = (const unsigned long long*)cur;
  unsigned long long t0[64];
#pragma unroll
  for (int q = 0; q < 32; ++q) {
    size_t base = (((size_t)(w * 32 + q)) * 128 + cl) * 2;  // in 8-byte units
    t0[2 * q + 0] = ld_h64(p + base);
    t0[2 * q + 1] = ld_h64(p + base + 1);
  }
#pragma unroll
  for (int q = 0; q < 64; ++q) {
    hreg[2 * q + 0] = __uint_as_float((unsigned)t0[q]);
    hreg[2 * q + 1] = __uint_as_float((unsigned)(t0[q] >> 32));
  }
}

__device__ __forceinline__ void gemm16(const float* __restrict__ Wg, const float hreg[128],
                                       float part[4][16][64], int hb, int w, int lane) {
  for (int r = 0; r < 16; ++r) {
    const float* wr = Wg + ((size_t)(hb * 16 + r)) * 512 + w * 128;  // wave-uniform -> s_load
    float a0 = 0.f, a1 = 0.f, a2 = 0.f, a3 = 0.f;
#pragma unroll
    for (int k = 0; k < 128; k += 4) {
      a0 = __builtin_fmaf(wr[k + 0], hreg[k + 0], a0);
      a1 = __builtin_fmaf(wr[k + 1], hreg[k + 1], a1);
      a2 = __builtin_fmaf(wr[k + 2], hreg[k + 2], a2);
      a3 = __builtin_fmaf(wr[k + 3], hreg[k + 3], a3);
    }
    part[w][r][lane] = (a0 + a1) + (a2 + a3);
  }
}

// ---------- main persistent recurrent kernel ----------
__global__ __launch_bounds__(256, 1) void k_rnn(
    const float* __restrict__ srcF, const float* __restrict__ WeG,
    const float* __restrict__ WdG, const float* __restrict__ WihEG,
    const float* __restrict__ bEG, const float* __restrict__ uDG,
    const float* __restrict__ bDG, const float* __restrict__ WfcF,
    float* __restrict__ hA, float* __restrict__ hB,
    void* __restrict__ outp, const int* __restrict__ flag,
    unsigned* __restrict__ arr, unsigned* __restrict__ rel) {
  const int bid = (int)blockIdx.x;
  const int hb  = bid >> 1;                      // h-group: gate rows hb*16 .. hb*16+15
  const int c0  = (bid & 1) << 6;                // batch offset 0 or 64
  const int lane = (int)threadIdx.x & 63;
  const int w   = __builtin_amdgcn_readfirstlane((int)threadIdx.x >> 6);  // k-slice / jj
  const int cl  = c0 + lane;                     // global batch col
  const int jj  = w;                             // h-row within group

  __shared__ float part[4][16][64];
  __shared__ float predL[64];
  __shared__ float wihL[16][8];
  __shared__ float bEL[16], uDL[16], bDL[16];

  if (threadIdx.x < 128) {
    int r = (int)threadIdx.x >> 3, i = (int)threadIdx.x & 7;
    wihL[r][i] = WihEG[(hb * 16 + r) * 8 + i];
  } else if (threadIdx.x < 144) {
    int r = (int)threadIdx.x - 128;
    bEL[r] = bEG[hb * 16 + r];
    uDL[r] = uDG[hb * 16 + r];
    bDL[r] = bDG[hb * 16 + r];
  }
  const int isbf = *flag;
  __syncthreads();

  float cst = 0.0f;          // c-state for (h-row hb*4+jj, batch cl)
  unsigned round = 1;

  // ================= encoder: 512 steps =================
  for (int t = 0; t < 512; ++t) {
    const float* cur = (t & 1) ? hB : hA;
    float* nxt = (t & 1) ? hA : hB;
    if (t > 0) {
      float hreg[128];
      load_h(cur, hreg, w, cl);
      gemm16(WeG, hreg, part, hb, w, lane);
    } else {
#pragma unroll
      for (int r = 0; r < 16; ++r) part[w][r][lane] = 0.0f;   // h0 = 0
    }
    __syncthreads();
    {
      const float* sp = srcF + ((size_t)cl * 512 + t) * 8;
      float4 xa = *(const float4*)sp;
      float4 xb = *(const float4*)(sp + 4);
      float gate[4];
#pragma unroll
      for (int ty = 0; ty < 4; ++ty) {
        int r = ty * 4 + jj;
        float s = part[0][r][lane] + part[1][r][lane] + part[2][r][lane] + part[3][r][lane];
        s += bEL[r];
        s += wihL[r][0] * xa.x + wihL[r][1] * xa.y + wihL[r][2] * xa.z + wihL[r][3] * xa.w;
        s += wihL[r][4] * xb.x + wihL[r][5] * xb.y + wihL[r][6] * xb.z + wihL[r][7] * xb.w;
        gate[ty] = s;
      }
      float ig = sigm(gate[0]), fg = sigm(gate[1]);
      float gg = tanh_(gate[2]), og = sigm(gate[3]);
      cst = fg * cst + ig * gg;
      float hn = og * tanh_(cst);
      st_h32((unsigned*)&nxt[((size_t)(hb * 128 + cl)) * 4 + jj], __float_as_uint(hn));
    }
    grid_barrier(arr, rel, round++, bid);
  }

  // ================= decoder: 96 steps =================
  for (int d = 0; d < 96; ++d) {
    const float* cur = (d & 1) ? hB : hA;
    float* nxt = (d & 1) ? hA : hB;
    float hreg[128];
    load_h(cur, hreg, w, cl);
    // pred_{d-1} = sigmoid(h_d . Wfc + bfc), per-block for its 64 cols
    {
      float p0 = 0.f, p1 = 0.f, p2 = 0.f, p3 = 0.f;
      const float* wf = WfcF + w * 128;   // wave-uniform
#pragma unroll
      for (int k = 0; k < 128; k += 4) {
        p0 = __builtin_fmaf(wf[k + 0], hreg[k + 0], p0);
        p1 = __builtin_fmaf(wf[k + 1], hreg[k + 1], p1);
        p2 = __builtin_fmaf(wf[k + 2], hreg[k + 2], p2);
        p3 = __builtin_fmaf(wf[k + 3], hreg[k + 3], p3);
      }
      part[w][0][lane] = (p0 + p1) + (p2 + p3);
    }
    __syncthreads();
    if (threadIdx.x < 64) {
      float s = part[0][0][lane] + part[1][0][lane] + part[2][0][lane] + part[3][0][lane];
      predL[lane] = sigm(s + WfcF[512]);
    }
    __syncthreads();
    float xin = (d == 0) ? srcF[(size_t)cl * 4096 + 4088] : predL[lane];  // src[b][511][0]
    if (d > 0 && hb == 0 && jj == 0) {
      int oi = cl * 96 + (d - 1);
      if (isbf) ((__hip_bfloat16*)outp)[oi] = __float2bfloat16(predL[lane]);
      else      ((float*)outp)[oi] = predL[lane];
    }
    gemm16(WdG, hreg, part, hb, w, lane);
    __syncthreads();
    {
      float gate[4];
#pragma unroll
      for (int ty = 0; ty < 4; ++ty) {
        int r = ty * 4 + jj;
        float s = part[0][r][lane] + part[1][r][lane] + part[2][r][lane] + part[3][r][lane];
        s += xin * uDL[r] + bDL[r];
        gate[ty] = s;
      }
      float ig = sigm(gate[0]), fg = sigm(gate[1]);
      float gg = tanh_(gate[2]), og = sigm(gate[3]);
      cst = fg * cst + ig * gg;
      float hn = og * tanh_(cst);
      st_h32((unsigned*)&nxt[((size_t)(hb * 128 + cl)) * 4 + jj], __float_as_uint(hn));
    }
    grid_barrier(arr, rel, round++, bid);
  }

  // ================= epilogue: pred_95 from h_96 (in hA) =================
  if (hb == 0) {
    float hreg[128];
    load_h(hA, hreg, w, cl);
    float p0 = 0.f, p1 = 0.f, p2 = 0.f, p3 = 0.f;
    const float* wf = WfcF + w * 128;
#pragma unroll
    for (int k = 0; k < 128; k += 4) {
      p0 = __builtin_fmaf(wf[k + 0], hreg[k + 0], p0);
      p1 = __builtin_fmaf(wf[k + 1], hreg[k + 1], p1);
      p2 = __builtin_fmaf(wf[k + 2], hreg[k + 2], p2);
      p3 = __builtin_fmaf(wf[k + 3], hreg[k + 3], p3);
    }
    part[w][0][lane] = (p0 + p1) + (p2 + p3);
    __syncthreads();
    if (threadIdx.x < 64) {
      float s = part[0][0][lane] + part[1][0][lane] + part[2][0][lane] + part[3][0][lane];
      float p = sigm(s + WfcF[512]);
      int oi = cl * 96 + 95;
      if (isbf) ((__hip_bfloat16*)outp)[oi] = __float2bfloat16(p);
      else      ((float*)outp)[oi] = p;
    }
  }
}

// ---------- host ----------
extern "C" void kernel_launch(void* const* d_in, const int* in_sizes, int n_in,
                              void* d_out, int out_size, void* d_ws, size_t ws_size,
                              hipStream_t stream) {
  (void)in_sizes; (void)n_in; (void)out_size; (void)ws_size;
  char* ws = (char*)d_ws;
  int* flag = (int*)ws;
  unsigned* arr = (unsigned*)(ws + 128);                 // 256 flags x 128 B = 32 KB
  unsigned* rel = (unsigned*)(ws + 128 + 32768);
  float* f = (float*)(ws + 128 + 32768 + 128);
  float* srcF  = f;                         // 128*512*8   = 524288
  float* WeG   = srcF + 524288;             // 2048*512    = 1048576
  float* WdG   = WeG + 1048576;             // 1048576
  float* WihEG = WdG + 1048576;             // 2048*8      = 16384
  float* bEG   = WihEG + 16384;             // 2048
  float* uDG   = bEG + 2048;                // 2048
  float* bDG   = uDG + 2048;                // 2048
  float* WfcF  = bDG + 2048;                // 513 (pad to 520)
  float* hA    = WfcF + 520;                // 128*128*4   = 65536
  float* hB    = hA + 65536;                // 65536

  // inputs (setup_inputs order):
  // 0 src, 1 Wih_e, 2 Whh_e, 3 bih_e, 4 bhh_e, 5 Wih_d, 6 Whh_d, 7 bih_d, 8 bhh_d,
  // 9 Wp, 10 bp, 11 Wfc, 12 bfc
  k_probe<<<dim3(1), dim3(256), 0, stream>>>((const unsigned int*)d_in[0], flag);
  k_prep_rows<<<dim3(2048), dim3(256), 0, stream>>>(
      d_in[2], d_in[6], d_in[1], d_in[5], d_in[3], d_in[4], d_in[7], d_in[8],
      d_in[9], d_in[10], WeG, WdG, WihEG, bEG, uDG, bDG, flag);
  k_prep_src<<<dim3(1026), dim3(256), 0, stream>>>(
      d_in[0], d_in[11], d_in[12], srcF, WfcF, arr, rel, flag);
  k_rnn<<<dim3(256), dim3(256), 0, stream>>>(
      srcF, WeG, WdG, WihEG, bEG, uDG, bDG, WfcF, hA, hB, d_out, flag, arr, rel);
}

// Round 4
// 7532.755 us; speedup vs baseline: 6.6211x; 1.3469x over previous
//
#include <hip/hip_runtime.h>
#include <hip/hip_bf16.h>

// ForecastNetSimple: B=128, T=512, I=8, H=512, W=96
// Persistent kernel, 256 blocks x 512 threads (8 waves, 2/SIMD).
// Distributed dataflow sync: per-block monotone step flags; each wave polls only
// its 16 producer blocks (the ones writing its k-slice), no central barrier,
// no release broadcast. Cross-block data (h, flags) via relaxed AGENT-scope
// atomics (bypass stale per-XCD L1/L2, served at the device coherence point).
// Weights stay L2-resident (normal cached s_load path).

#define FLAG_STRIDE 32  // dwords (128 B) between per-block flags

// ---------- dtype-flexible load (flag: 1 = inputs are bf16, 0 = fp32) ----------
__device__ __forceinline__ float ldf(const void* p, size_t i, int isbf) {
  if (isbf) return __bfloat162float(((const __hip_bfloat16*)p)[i]);
  return ((const float*)p)[i];
}

// ---------- coherent helpers ----------
__device__ __forceinline__ unsigned ld_flag(const unsigned* p) {
  return __hip_atomic_load(p, __ATOMIC_RELAXED, __HIP_MEMORY_SCOPE_AGENT);
}
__device__ __forceinline__ void st_flag(unsigned* p, unsigned v) {
  __hip_atomic_store(p, v, __ATOMIC_RELAXED, __HIP_MEMORY_SCOPE_AGENT);
}
__device__ __forceinline__ unsigned long long ld_h64(const unsigned long long* p) {
  return __hip_atomic_load(p, __ATOMIC_RELAXED, __HIP_MEMORY_SCOPE_AGENT);
}
__device__ __forceinline__ void st_h32(unsigned* p, unsigned v) {
  __hip_atomic_store(p, v, __ATOMIC_RELAXED, __HIP_MEMORY_SCOPE_AGENT);
}

// ---------- probe: bf16 vs fp32 input buffers ----------
__global__ void k_probe(const unsigned int* __restrict__ src_raw, int* __restrict__ flag) {
  __shared__ int cnt;
  if (threadIdx.x == 0) cnt = 0;
  __syncthreads();
  int c = 0;
  for (int i = threadIdx.x; i < 512; i += 256) {
    unsigned v = src_raw[i];
    float f = __uint_as_float((v & 0xffffu) << 16);
    float a = fabsf(f);
    if (a > 0.00390625f && a < 4.0f) c++;
  }
  atomicAdd(&cnt, c);
  __syncthreads();
  if (threadIdx.x == 0) *flag = (cnt > 256) ? 1 : 0;
}

// ---------- weight gather/convert ----------
// Dest row d = hb*16 + r, r = type*4 + jj -> source gate row g = type*512 + hb*4 + jj
__global__ void k_prep_rows(const void* __restrict__ Whh_e, const void* __restrict__ Whh_d,
                            const void* __restrict__ Wih_e, const void* __restrict__ Wih_d,
                            const void* __restrict__ bih_e, const void* __restrict__ bhh_e,
                            const void* __restrict__ bih_d, const void* __restrict__ bhh_d,
                            const void* __restrict__ Wp,    const void* __restrict__ bp,
                            float* __restrict__ WeG, float* __restrict__ WdG,
                            float* __restrict__ WihEG, float* __restrict__ bEG,
                            float* __restrict__ uDG, float* __restrict__ bDG,
                            const int* __restrict__ flag) {
  const int isbf = *flag;
  const int d = blockIdx.x;
  const int hb = d >> 4, r = d & 15, type = r >> 2, jj = r & 3;
  const int g = type * 512 + hb * 4 + jj;
  for (int k = threadIdx.x; k < 512; k += 256) {
    WeG[(size_t)d * 512 + k] = ldf(Whh_e, (size_t)g * 512 + k, isbf);
    WdG[(size_t)d * 512 + k] = ldf(Whh_d, (size_t)g * 512 + k, isbf);
  }
  if (threadIdx.x < 8)
    WihEG[d * 8 + threadIdx.x] = ldf(Wih_e, (size_t)g * 8 + threadIdx.x, isbf);
  if (threadIdx.x == 0) {
    bEG[d] = ldf(bih_e, g, isbf) + ldf(bhh_e, g, isbf);
    float u = 0.f, w0 = 0.f;
    for (int i = 0; i < 8; ++i) {
      float wv = ldf(Wih_d, (size_t)g * 8 + i, isbf);
      u  += wv * ldf(Wp, i, isbf);
      w0 += wv * ldf(bp, i, isbf);
    }
    uDG[d] = u;
    bDG[d] = ldf(bih_d, g, isbf) + ldf(bhh_d, g, isbf) + w0;
  }
}

// ---------- src/Wfc convert + flag init ----------
__global__ void k_prep_src(const void* __restrict__ src, const void* __restrict__ Wfc,
                           const void* __restrict__ bfc, float* __restrict__ srcF,
                           float* __restrict__ WfcF, unsigned* __restrict__ arr,
                           const int* __restrict__ flag) {
  const int isbf = *flag;
  const int b = blockIdx.x;
  if (b < 1024) {
    int i = b * 256 + threadIdx.x;
    srcF[i] = ldf(src, i, isbf);
  } else if (b == 1024) {
    for (int k = threadIdx.x; k < 512; k += 256) WfcF[k] = ldf(Wfc, k, isbf);
    if (threadIdx.x == 0) WfcF[512] = ldf(bfc, 0, isbf);
  } else {
    for (int k = threadIdx.x; k < 256 * FLAG_STRIDE; k += 256) arr[k] = 0u;
  }
}

// ---------- math helpers ----------
__device__ __forceinline__ float sigm(float x) { return 1.0f / (1.0f + __expf(-x)); }
__device__ __forceinline__ float tanh_(float x) {
  float ax = fabsf(x);
  float e = __expf(-2.0f * ax);
  float t = (1.0f - e) / (1.0f + e);
  return copysignf(t, x);
}

// ---------- wave-level producer wait: 16 flags, one per lane (lanes mod 16) ----------
__device__ __forceinline__ void wait_producers(const unsigned* pflag, unsigned n) {
  while (!__all((int)(ld_flag(pflag) >= n))) __builtin_amdgcn_s_sleep(1);
  asm volatile("" ::: "memory");
}

// ---------- coherent h load: 64 floats (k = w*64 .. w*64+63) for batch col cl ----------
__device__ __forceinline__ void load_h(const float* __restrict__ cur, float hreg[64],
                                       int w, int cl) {
  const unsigned long long* p = (const unsigned long long*)cur;
  unsigned long long t0[32];
#pragma unroll
  for (int q = 0; q < 16; ++q) {
    size_t base = (((size_t)(w * 16 + q)) * 128 + cl) * 2;  // 8-byte units
    t0[2 * q + 0] = ld_h64(p + base);
    t0[2 * q + 1] = ld_h64(p + base + 1);
  }
#pragma unroll
  for (int q = 0; q < 32; ++q) {
    hreg[2 * q + 0] = __uint_as_float((unsigned)t0[q]);
    hreg[2 * q + 1] = __uint_as_float((unsigned)(t0[q] >> 32));
  }
}

__device__ __forceinline__ void gemm16(const float* __restrict__ Wg, const float hreg[64],
                                       float part[8][16][64], int hb, int w, int lane) {
  for (int r = 0; r < 16; ++r) {
    const float* wr = Wg + ((size_t)(hb * 16 + r)) * 512 + w * 64;  // wave-uniform -> s_load
    float a0 = 0.f, a1 = 0.f, a2 = 0.f, a3 = 0.f;
#pragma unroll
    for (int k = 0; k < 64; k += 4) {
      a0 = __builtin_fmaf(wr[k + 0], hreg[k + 0], a0);
      a1 = __builtin_fmaf(wr[k + 1], hreg[k + 1], a1);
      a2 = __builtin_fmaf(wr[k + 2], hreg[k + 2], a2);
      a3 = __builtin_fmaf(wr[k + 3], hreg[k + 3], a3);
    }
    part[w][r][lane] = (a0 + a1) + (a2 + a3);
  }
}

// ---------- main persistent recurrent kernel ----------
__global__ __launch_bounds__(512, 2) void k_rnn(
    const float* __restrict__ srcF, const float* __restrict__ WeG,
    const float* __restrict__ WdG, const float* __restrict__ WihEG,
    const float* __restrict__ bEG, const float* __restrict__ uDG,
    const float* __restrict__ bDG, const float* __restrict__ WfcF,
    float* __restrict__ hA, float* __restrict__ hB,
    void* __restrict__ outp, const int* __restrict__ flag,
    unsigned* __restrict__ arr) {
  const int bid  = (int)blockIdx.x;
  const int hb   = bid >> 1;                     // produces h rows hb*4 .. hb*4+3
  const int half = bid & 1;                      // batch half
  const int tid  = (int)threadIdx.x;
  const int lane = tid & 63;
  const int w    = __builtin_amdgcn_readfirstlane(tid >> 6);  // wave 0..7, k-slice 64w..
  const int cl   = (half << 6) + lane;           // global batch col

  __shared__ float part[8][16][64];
  __shared__ float predP[8][64];
  __shared__ float predL[64];
  __shared__ float wihL[16][8];
  __shared__ float bEL[16], uDL[16], bDL[16];

  if (tid < 128) {
    int r = tid >> 3, i = tid & 7;
    wihL[r][i] = WihEG[(hb * 16 + r) * 8 + i];
  } else if (tid < 144) {
    int r = tid - 128;
    bEL[r] = bEG[hb * 16 + r];
    uDL[r] = uDG[hb * 16 + r];
    bDL[r] = bDG[hb * 16 + r];
  }
  const int isbf = *flag;
  // wave w consumes h rows from blocks hb' in [16w, 16w+16), same half
  const unsigned* pflag = arr + (size_t)((16 * w + (lane & 15)) * 2 + half) * FLAG_STRIDE;
  unsigned* myflag = arr + (size_t)bid * FLAG_STRIDE;
  __syncthreads();

  float cst = 0.0f;   // c-state for (h-row hb*4+w, batch cl) -- waves 0..3 only

  // ================= encoder: 512 steps =================
  for (int t = 0; t < 512; ++t) {
    const float* cur = (t & 1) ? hB : hA;        // h_t
    float* nxt = (t & 1) ? hA : hB;              // h_{t+1}
    if (t > 0) {
      wait_producers(pflag, (unsigned)t);
      float hreg[64];
      load_h(cur, hreg, w, cl);
      gemm16(WeG, hreg, part, hb, w, lane);
    } else {
#pragma unroll
      for (int r = 0; r < 16; ++r) part[w][r][lane] = 0.0f;   // h0 = 0
    }
    __syncthreads();
    if (w < 4) {
      const int jj = w;
      const float* sp = srcF + ((size_t)cl * 512 + t) * 8;
      float4 xa = *(const float4*)sp;
      float4 xb = *(const float4*)(sp + 4);
      float gate[4];
#pragma unroll
      for (int ty = 0; ty < 4; ++ty) {
        int r = ty * 4 + jj;
        float s = 0.f;
#pragma unroll
        for (int w2 = 0; w2 < 8; ++w2) s += part[w2][r][lane];
        s += bEL[r];
        s += wihL[r][0] * xa.x + wihL[r][1] * xa.y + wihL[r][2] * xa.z + wihL[r][3] * xa.w;
        s += wihL[r][4] * xb.x + wihL[r][5] * xb.y + wihL[r][6] * xb.z + wihL[r][7] * xb.w;
        gate[ty] = s;
      }
      float ig = sigm(gate[0]), fg = sigm(gate[1]);
      float gg = tanh_(gate[2]), og = sigm(gate[3]);
      cst = fg * cst + ig * gg;
      float hn = og * tanh_(cst);
      st_h32((unsigned*)&nxt[((size_t)(hb * 128 + cl)) * 4 + jj], __float_as_uint(hn));
    }
    asm volatile("s_waitcnt vmcnt(0)" ::: "memory");  // own stores at coherence point
    __syncthreads();                                   // whole block done
    if (tid == 0) st_flag(myflag, (unsigned)(t + 1));
  }

  // ================= decoder: 96 steps =================
  for (int d = 0; d < 96; ++d) {
    const int n = 512 + d;                        // reads h_n, writes h_{n+1}
    const float* cur = (n & 1) ? hB : hA;
    float* nxt = (n & 1) ? hA : hB;
    wait_producers(pflag, (unsigned)n);
    float hreg[64];
    load_h(cur, hreg, w, cl);
    {
      const float* wf = WfcF + w * 64;            // wave-uniform
      float p0 = 0.f, p1 = 0.f, p2 = 0.f, p3 = 0.f;
#pragma unroll
      for (int k = 0; k < 64; k += 4) {
        p0 = __builtin_fmaf(wf[k + 0], hreg[k + 0], p0);
        p1 = __builtin_fmaf(wf[k + 1], hreg[k + 1], p1);
        p2 = __builtin_fmaf(wf[k + 2], hreg[k + 2], p2);
        p3 = __builtin_fmaf(wf[k + 3], hreg[k + 3], p3);
      }
      predP[w][lane] = (p0 + p1) + (p2 + p3);
    }
    gemm16(WdG, hreg, part, hb, w, lane);
    __syncthreads();
    if (tid < 64) {
      float s = 0.f;
#pragma unroll
      for (int w2 = 0; w2 < 8; ++w2) s += predP[w2][lane];
      float pr = sigm(s + WfcF[512]);
      predL[lane] = pr;
      if (hb == 0 && d > 0) {                     // pred_{d-1}, blocks 0/1 only
        int oi = cl * 96 + (d - 1);
        if (isbf) ((__hip_bfloat16*)outp)[oi] = __float2bfloat16(pr);
        else      ((float*)outp)[oi] = pr;
      }
    }
    __syncthreads();
    if (w < 4) {
      const int jj = w;
      float xin = (d == 0) ? srcF[(size_t)cl * 4096 + 4088] : predL[lane];  // src[b][511][0]
      float gate[4];
#pragma unroll
      for (int ty = 0; ty < 4; ++ty) {
        int r = ty * 4 + jj;
        float s = 0.f;
#pragma unroll
        for (int w2 = 0; w2 < 8; ++w2) s += part[w2][r][lane];
        s += xin * uDL[r] + bDL[r];
        gate[ty] = s;
      }
      float ig = sigm(gate[0]), fg = sigm(gate[1]);
      float gg = tanh_(gate[2]), og = sigm(gate[3]);
      cst = fg * cst + ig * gg;
      float hn = og * tanh_(cst);
      st_h32((unsigned*)&nxt[((size_t)(hb * 128 + cl)) * 4 + jj], __float_as_uint(hn));
    }
    asm volatile("s_waitcnt vmcnt(0)" ::: "memory");
    __syncthreads();
    if (tid == 0) st_flag(myflag, (unsigned)(n + 1));
  }

  // ================= epilogue: pred_95 from h_608 (in hA) =================
  if (hb == 0) {
    wait_producers(pflag, 608u);
    float hreg[64];
    load_h(hA, hreg, w, cl);
    const float* wf = WfcF + w * 64;
    float p0 = 0.f, p1 = 0.f, p2 = 0.f, p3 = 0.f;
#pragma unroll
    for (int k = 0; k < 64; k += 4) {
      p0 = __builtin_fmaf(wf[k + 0], hreg[k + 0], p0);
      p1 = __builtin_fmaf(wf[k + 1], hreg[k + 1], p1);
      p2 = __builtin_fmaf(wf[k + 2], hreg[k + 2], p2);
      p3 = __builtin_fmaf(wf[k + 3], hreg[k + 3], p3);
    }
    predP[w][lane] = (p0 + p1) + (p2 + p3);
    __syncthreads();
    if (tid < 64) {
      float s = 0.f;
#pragma unroll
      for (int w2 = 0; w2 < 8; ++w2) s += predP[w2][lane];
      float pr = sigm(s + WfcF[512]);
      int oi = cl * 96 + 95;
      if (isbf) ((__hip_bfloat16*)outp)[oi] = __float2bfloat16(pr);
      else      ((float*)outp)[oi] = pr;
    }
  }
}

// ---------- host ----------
extern "C" void kernel_launch(void* const* d_in, const int* in_sizes, int n_in,
                              void* d_out, int out_size, void* d_ws, size_t ws_size,
                              hipStream_t stream) {
  (void)in_sizes; (void)n_in; (void)out_size; (void)ws_size;
  char* ws = (char*)d_ws;
  int* flag = (int*)ws;
  unsigned* arr = (unsigned*)(ws + 128);                 // 256 flags x 128 B = 32 KB
  float* f = (float*)(ws + 128 + 32768 + 128);
  float* srcF  = f;                         // 128*512*8   = 524288
  float* WeG   = srcF + 524288;             // 2048*512    = 1048576
  float* WdG   = WeG + 1048576;             // 1048576
  float* WihEG = WdG + 1048576;             // 2048*8      = 16384
  float* bEG   = WihEG + 16384;             // 2048
  float* uDG   = bEG + 2048;                // 2048
  float* bDG   = uDG + 2048;                // 2048
  float* WfcF  = bDG + 2048;                // 513 (pad 520)
  float* hA    = WfcF + 520;                // 128*128*4   = 65536
  float* hB    = hA + 65536;                // 65536

  k_probe<<<dim3(1), dim3(256), 0, stream>>>((const unsigned int*)d_in[0], flag);
  k_prep_rows<<<dim3(2048), dim3(256), 0, stream>>>(
      d_in[2], d_in[6], d_in[1], d_in[5], d_in[3], d_in[4], d_in[7], d_in[8],
      d_in[9], d_in[10], WeG, WdG, WihEG, bEG, uDG, bDG, flag);
  k_prep_src<<<dim3(1026), dim3(256), 0, stream>>>(
      d_in[0], d_in[11], d_in[12], srcF, WfcF, arr, flag);
  k_rnn<<<dim3(256), dim3(512), 0, stream>>>(
      srcF, WeG, WdG, WihEG, bEG, uDG, bDG, WfcF, hA, hB, d_out, flag, arr);
}

// Round 5
// 7360.718 us; speedup vs baseline: 6.7759x; 1.0234x over previous
//
#include <hip/hip_runtime.h>
#include <hip/hip_bf16.h>

// ForecastNetSimple: B=128, T=512, I=8, H=512, W=96
// Persistent kernel, 256 blocks x 512 threads (8 waves, 1 block/CU).
// Distributed dataflow sync with CENTRALIZED per-block polling: wave 0 polls all
// 128 same-half producer flags (2 per lane), releases sibling waves via an LDS
// word. Whh weight tiles staged in LDS once (64 KB) -> hot loop is
// ds_read_b128 (uniform broadcast) + v_fmac, no per-step scalar-load stream.
// Cross-block data (h, flags) via relaxed AGENT-scope atomics (bypass stale
// per-XCD L1/L2, served at the device coherence point).

#define FLAG_STRIDE 32  // dwords (128 B) between per-block flags

// ---------- dtype-flexible load (flag: 1 = inputs are bf16, 0 = fp32) ----------
__device__ __forceinline__ float ldf(const void* p, size_t i, int isbf) {
  if (isbf) return __bfloat162float(((const __hip_bfloat16*)p)[i]);
  return ((const float*)p)[i];
}

// ---------- coherent helpers ----------
__device__ __forceinline__ unsigned ld_flag(const unsigned* p) {
  return __hip_atomic_load(p, __ATOMIC_RELAXED, __HIP_MEMORY_SCOPE_AGENT);
}
__device__ __forceinline__ void st_flag(unsigned* p, unsigned v) {
  __hip_atomic_store(p, v, __ATOMIC_RELAXED, __HIP_MEMORY_SCOPE_AGENT);
}
__device__ __forceinline__ unsigned long long ld_h64(const unsigned long long* p) {
  return __hip_atomic_load(p, __ATOMIC_RELAXED, __HIP_MEMORY_SCOPE_AGENT);
}
__device__ __forceinline__ void st_h32(unsigned* p, unsigned v) {
  __hip_atomic_store(p, v, __ATOMIC_RELAXED, __HIP_MEMORY_SCOPE_AGENT);
}

// ---------- probe: bf16 vs fp32 input buffers ----------
__global__ void k_probe(const unsigned int* __restrict__ src_raw, int* __restrict__ flag) {
  __shared__ int cnt;
  if (threadIdx.x == 0) cnt = 0;
  __syncthreads();
  int c = 0;
  for (int i = threadIdx.x; i < 512; i += 256) {
    unsigned v = src_raw[i];
    float f = __uint_as_float((v & 0xffffu) << 16);
    float a = fabsf(f);
    if (a > 0.00390625f && a < 4.0f) c++;
  }
  atomicAdd(&cnt, c);
  __syncthreads();
  if (threadIdx.x == 0) *flag = (cnt > 256) ? 1 : 0;
}

// ---------- weight gather/convert ----------
// Dest row d = hb*16 + r, r = type*4 + jj -> source gate row g = type*512 + hb*4 + jj
__global__ void k_prep_rows(const void* __restrict__ Whh_e, const void* __restrict__ Whh_d,
                            const void* __restrict__ Wih_e, const void* __restrict__ Wih_d,
                            const void* __restrict__ bih_e, const void* __restrict__ bhh_e,
                            const void* __restrict__ bih_d, const void* __restrict__ bhh_d,
                            const void* __restrict__ Wp,    const void* __restrict__ bp,
                            float* __restrict__ WeG, float* __restrict__ WdG,
                            float* __restrict__ WihEG, float* __restrict__ bEG,
                            float* __restrict__ uDG, float* __restrict__ bDG,
                            const int* __restrict__ flag) {
  const int isbf = *flag;
  const int d = blockIdx.x;
  const int hb = d >> 4, r = d & 15, type = r >> 2, jj = r & 3;
  const int g = type * 512 + hb * 4 + jj;
  for (int k = threadIdx.x; k < 512; k += 256) {
    WeG[(size_t)d * 512 + k] = ldf(Whh_e, (size_t)g * 512 + k, isbf);
    WdG[(size_t)d * 512 + k] = ldf(Whh_d, (size_t)g * 512 + k, isbf);
  }
  if (threadIdx.x < 8)
    WihEG[d * 8 + threadIdx.x] = ldf(Wih_e, (size_t)g * 8 + threadIdx.x, isbf);
  if (threadIdx.x == 0) {
    bEG[d] = ldf(bih_e, g, isbf) + ldf(bhh_e, g, isbf);
    float u = 0.f, w0 = 0.f;
    for (int i = 0; i < 8; ++i) {
      float wv = ldf(Wih_d, (size_t)g * 8 + i, isbf);
      u  += wv * ldf(Wp, i, isbf);
      w0 += wv * ldf(bp, i, isbf);
    }
    uDG[d] = u;
    bDG[d] = ldf(bih_d, g, isbf) + ldf(bhh_d, g, isbf) + w0;
  }
}

// ---------- src/Wfc convert + flag init ----------
__global__ void k_prep_src(const void* __restrict__ src, const void* __restrict__ Wfc,
                           const void* __restrict__ bfc, float* __restrict__ srcF,
                           float* __restrict__ WfcF, unsigned* __restrict__ arr,
                           const int* __restrict__ flag) {
  const int isbf = *flag;
  const int b = blockIdx.x;
  if (b < 1024) {
    int i = b * 256 + threadIdx.x;
    srcF[i] = ldf(src, i, isbf);
  } else if (b == 1024) {
    for (int k = threadIdx.x; k < 512; k += 256) WfcF[k] = ldf(Wfc, k, isbf);
    if (threadIdx.x == 0) WfcF[512] = ldf(bfc, 0, isbf);
  } else {
    for (int k = threadIdx.x; k < 256 * FLAG_STRIDE; k += 256) arr[k] = 0u;
  }
}

// ---------- math helpers ----------
__device__ __forceinline__ float sigm(float x) { return 1.0f / (1.0f + __expf(-x)); }
__device__ __forceinline__ float tanh_(float x) {
  float ax = fabsf(x);
  float e = __expf(-2.0f * ax);
  float t = (1.0f - e) / (1.0f + e);
  return copysignf(t, x);
}

// ---------- coherent h load: 64 floats (k = w*64 .. w*64+63) for batch col cl ----------
__device__ __forceinline__ void load_h(const float* __restrict__ cur, float hreg[64],
                                       int w, int cl) {
  const unsigned long long* p = (const unsigned long long*)cur;
  unsigned long long t0[32];
#pragma unroll
  for (int q = 0; q < 16; ++q) {
    size_t base = (((size_t)(w * 16 + q)) * 128 + cl) * 2;  // 8-byte units
    t0[2 * q + 0] = ld_h64(p + base);
    t0[2 * q + 1] = ld_h64(p + base + 1);
  }
#pragma unroll
  for (int q = 0; q < 32; ++q) {
    hreg[2 * q + 0] = __uint_as_float((unsigned)t0[q]);
    hreg[2 * q + 1] = __uint_as_float((unsigned)(t0[q] >> 32));
  }
}

// ---------- GEMM partial from LDS-staged weights (uniform-address broadcast reads) ----------
__device__ __forceinline__ void gemm16_lds(const float* __restrict__ WL,  // [16][512] in LDS
                                           const float hreg[64],
                                           float part[8][16][64], int w, int lane) {
  for (int r = 0; r < 16; ++r) {
    const float* wr = WL + r * 512 + w * 64;   // wave-uniform LDS address
    float a0 = 0.f, a1 = 0.f, a2 = 0.f, a3 = 0.f;
#pragma unroll
    for (int k = 0; k < 64; k += 4) {
      float4 wv = *(const float4*)(wr + k);    // ds_read_b128, broadcast
      a0 = __builtin_fmaf(wv.x, hreg[k + 0], a0);
      a1 = __builtin_fmaf(wv.y, hreg[k + 1], a1);
      a2 = __builtin_fmaf(wv.z, hreg[k + 2], a2);
      a3 = __builtin_fmaf(wv.w, hreg[k + 3], a3);
    }
    part[w][r][lane] = (a0 + a1) + (a2 + a3);
  }
}

// ---------- main persistent recurrent kernel ----------
__global__ __launch_bounds__(512, 2) void k_rnn(
    const float* __restrict__ srcF, const float* __restrict__ WeG,
    const float* __restrict__ WdG, const float* __restrict__ WihEG,
    const float* __restrict__ bEG, const float* __restrict__ uDG,
    const float* __restrict__ bDG, const float* __restrict__ WfcF,
    float* __restrict__ hA, float* __restrict__ hB,
    void* __restrict__ outp, const int* __restrict__ flag,
    unsigned* __restrict__ arr) {
  const int bid  = (int)blockIdx.x;
  const int hb   = bid >> 1;                     // produces h rows hb*4 .. hb*4+3
  const int half = bid & 1;                      // batch half
  const int tid  = (int)threadIdx.x;
  const int lane = tid & 63;
  const int w    = __builtin_amdgcn_readfirstlane(tid >> 6);  // wave 0..7
  const int cl   = (half << 6) + lane;           // global batch col

  __shared__ float WeL[16 * 512];                // 32 KB: this block's encoder rows
  __shared__ float WdL[16 * 512];                // 32 KB: decoder rows
  __shared__ float WfcL[516];
  __shared__ float part[8][16][64];
  __shared__ float predP[8][64];
  __shared__ float predL[64];
  __shared__ float wihL[16][8];
  __shared__ float bEL[16], uDL[16], bDL[16];
  __shared__ unsigned relstep;

  // ---- one-time staging ----
  {
    const float4* se = (const float4*)(WeG + (size_t)hb * 8192);
    const float4* sd = (const float4*)(WdG + (size_t)hb * 8192);
    float4* de = (float4*)WeL;
    float4* dd = (float4*)WdL;
    for (int i = tid; i < 2048; i += 512) { de[i] = se[i]; dd[i] = sd[i]; }
    if (tid < 513) WfcL[tid] = WfcF[tid];
    if (tid < 128) {
      int r = tid >> 3, i = tid & 7;
      wihL[r][i] = WihEG[(hb * 16 + r) * 8 + i];
    }
    if (tid >= 128 && tid < 144) {
      int r = tid - 128;
      bEL[r] = bEG[hb * 16 + r];
      uDL[r] = uDG[hb * 16 + r];
      bDL[r] = bDG[hb * 16 + r];
    }
    if (tid == 0) relstep = 0u;
  }
  const int isbf = *flag;
  // wave 0 polls all 128 same-half producer flags: lane l -> blocks (l, l+64) of this half
  const unsigned* pf1 = arr + (size_t)(lane * 2 + half) * FLAG_STRIDE;
  const unsigned* pf2 = arr + (size_t)((lane + 64) * 2 + half) * FLAG_STRIDE;
  unsigned* myflag = arr + (size_t)bid * FLAG_STRIDE;
  __syncthreads();

  float cst = 0.0f;   // c-state for (h-row hb*4+w, batch cl) -- waves 0..3 only

#define BLOCK_WAIT(n)                                                          \
  do {                                                                         \
    unsigned _n = (unsigned)(n);                                               \
    if (w == 0) {                                                              \
      while (!__all((int)(ld_flag(pf1) >= _n && ld_flag(pf2) >= _n)))          \
        __builtin_amdgcn_s_sleep(2);                                           \
      asm volatile("" ::: "memory");                                           \
      if (lane == 0)                                                           \
        __hip_atomic_store(&relstep, _n, __ATOMIC_RELEASE,                     \
                           __HIP_MEMORY_SCOPE_WORKGROUP);                      \
    } else {                                                                   \
      while (__hip_atomic_load(&relstep, __ATOMIC_ACQUIRE,                     \
                               __HIP_MEMORY_SCOPE_WORKGROUP) < _n)             \
        __builtin_amdgcn_s_sleep(1);                                           \
    }                                                                          \
  } while (0)

  // ================= encoder: 512 steps =================
  for (int t = 0; t < 512; ++t) {
    const float* cur = (t & 1) ? hB : hA;        // h_t
    float* nxt = (t & 1) ? hA : hB;              // h_{t+1}
    if (t > 0) {
      BLOCK_WAIT(t);
      float hreg[64];
      load_h(cur, hreg, w, cl);
      gemm16_lds(WeL, hreg, part, w, lane);
    } else {
#pragma unroll
      for (int r = 0; r < 16; ++r) part[w][r][lane] = 0.0f;   // h0 = 0
    }
    __syncthreads();
    if (w < 4) {
      const int jj = w;
      const float* sp = srcF + ((size_t)cl * 512 + t) * 8;
      float4 xa = *(const float4*)sp;
      float4 xb = *(const float4*)(sp + 4);
      float gate[4];
#pragma unroll
      for (int ty = 0; ty < 4; ++ty) {
        int r = ty * 4 + jj;
        float s = 0.f;
#pragma unroll
        for (int w2 = 0; w2 < 8; ++w2) s += part[w2][r][lane];
        s += bEL[r];
        s += wihL[r][0] * xa.x + wihL[r][1] * xa.y + wihL[r][2] * xa.z + wihL[r][3] * xa.w;
        s += wihL[r][4] * xb.x + wihL[r][5] * xb.y + wihL[r][6] * xb.z + wihL[r][7] * xb.w;
        gate[ty] = s;
      }
      float ig = sigm(gate[0]), fg = sigm(gate[1]);
      float gg = tanh_(gate[2]), og = sigm(gate[3]);
      cst = fg * cst + ig * gg;
      float hn = og * tanh_(cst);
      st_h32((unsigned*)&nxt[((size_t)(hb * 128 + cl)) * 4 + jj], __float_as_uint(hn));
    }
    asm volatile("s_waitcnt vmcnt(0)" ::: "memory");  // h stores/loads drained
    __syncthreads();
    if (tid == 0) st_flag(myflag, (unsigned)(t + 1));
  }

  // ================= decoder: 96 steps =================
  for (int d = 0; d < 96; ++d) {
    const int n = 512 + d;                        // reads h_n, writes h_{n+1}
    const float* cur = (n & 1) ? hB : hA;
    float* nxt = (n & 1) ? hA : hB;
    BLOCK_WAIT(n);
    float hreg[64];
    load_h(cur, hreg, w, cl);
    {
      const float* wf = WfcL + w * 64;            // wave-uniform LDS
      float p0 = 0.f, p1 = 0.f, p2 = 0.f, p3 = 0.f;
#pragma unroll
      for (int k = 0; k < 64; k += 4) {
        float4 wv = *(const float4*)(wf + k);
        p0 = __builtin_fmaf(wv.x, hreg[k + 0], p0);
        p1 = __builtin_fmaf(wv.y, hreg[k + 1], p1);
        p2 = __builtin_fmaf(wv.z, hreg[k + 2], p2);
        p3 = __builtin_fmaf(wv.w, hreg[k + 3], p3);
      }
      predP[w][lane] = (p0 + p1) + (p2 + p3);
    }
    gemm16_lds(WdL, hreg, part, w, lane);
    __syncthreads();
    if (tid < 64) {
      float s = 0.f;
#pragma unroll
      for (int w2 = 0; w2 < 8; ++w2) s += predP[w2][lane];
      float pr = sigm(s + WfcL[512]);
      predL[lane] = pr;
      if (hb == 0 && d > 0) {                     // pred_{d-1}, blocks 0/1 only
        int oi = cl * 96 + (d - 1);
        if (isbf) ((__hip_bfloat16*)outp)[oi] = __float2bfloat16(pr);
        else      ((float*)outp)[oi] = pr;
      }
    }
    __syncthreads();
    if (w < 4) {
      const int jj = w;
      float xin = (d == 0) ? srcF[(size_t)cl * 4096 + 4088] : predL[lane];  // src[b][511][0]
      float gate[4];
#pragma unroll
      for (int ty = 0; ty < 4; ++ty) {
        int r = ty * 4 + jj;
        float s = 0.f;
#pragma unroll
        for (int w2 = 0; w2 < 8; ++w2) s += part[w2][r][lane];
        s += xin * uDL[r] + bDL[r];
        gate[ty] = s;
      }
      float ig = sigm(gate[0]), fg = sigm(gate[1]);
      float gg = tanh_(gate[2]), og = sigm(gate[3]);
      cst = fg * cst + ig * gg;
      float hn = og * tanh_(cst);
      st_h32((unsigned*)&nxt[((size_t)(hb * 128 + cl)) * 4 + jj], __float_as_uint(hn));
    }
    asm volatile("s_waitcnt vmcnt(0)" ::: "memory");
    __syncthreads();
    if (tid == 0) st_flag(myflag, (unsigned)(n + 1));
  }

  // ================= epilogue: pred_95 from h_608 (in hA) =================
  if (hb == 0) {
    BLOCK_WAIT(608u);
    float hreg[64];
    load_h(hA, hreg, w, cl);
    const float* wf = WfcL + w * 64;
    float p0 = 0.f, p1 = 0.f, p2 = 0.f, p3 = 0.f;
#pragma unroll
    for (int k = 0; k < 64; k += 4) {
      float4 wv = *(const float4*)(wf + k);
      p0 = __builtin_fmaf(wv.x, hreg[k + 0], p0);
      p1 = __builtin_fmaf(wv.y, hreg[k + 1], p1);
      p2 = __builtin_fmaf(wv.z, hreg[k + 2], p2);
      p3 = __builtin_fmaf(wv.w, hreg[k + 3], p3);
    }
    predP[w][lane] = (p0 + p1) + (p2 + p3);
    __syncthreads();
    if (tid < 64) {
      float s = 0.f;
#pragma unroll
      for (int w2 = 0; w2 < 8; ++w2) s += predP[w2][lane];
      float pr = sigm(s + WfcL[512]);
      int oi = cl * 96 + 95;
      if (isbf) ((__hip_bfloat16*)outp)[oi] = __float2bfloat16(pr);
      else      ((float*)outp)[oi] = pr;
    }
  }
#undef BLOCK_WAIT
}

// ---------- host ----------
extern "C" void kernel_launch(void* const* d_in, const int* in_sizes, int n_in,
                              void* d_out, int out_size, void* d_ws, size_t ws_size,
                              hipStream_t stream) {
  (void)in_sizes; (void)n_in; (void)out_size; (void)ws_size;
  char* ws = (char*)d_ws;
  int* flag = (int*)ws;
  unsigned* arr = (unsigned*)(ws + 128);                 // 256 flags x 128 B = 32 KB
  float* f = (float*)(ws + 128 + 32768 + 128);
  float* srcF  = f;                         // 128*512*8   = 524288
  float* WeG   = srcF + 524288;             // 2048*512    = 1048576
  float* WdG   = WeG + 1048576;             // 1048576
  float* WihEG = WdG + 1048576;             // 2048*8      = 16384
  float* bEG   = WihEG + 16384;             // 2048
  float* uDG   = bEG + 2048;                // 2048
  float* bDG   = uDG + 2048;                // 2048
  float* WfcF  = bDG + 2048;                // 513 (pad 520)
  float* hA    = WfcF + 520;                // 128*128*4   = 65536
  float* hB    = hA + 65536;                // 65536

  k_probe<<<dim3(1), dim3(256), 0, stream>>>((const unsigned int*)d_in[0], flag);
  k_prep_rows<<<dim3(2048), dim3(256), 0, stream>>>(
      d_in[2], d_in[6], d_in[1], d_in[5], d_in[3], d_in[4], d_in[7], d_in[8],
      d_in[9], d_in[10], WeG, WdG, WihEG, bEG, uDG, bDG, flag);
  k_prep_src<<<dim3(1026), dim3(256), 0, stream>>>(
      d_in[0], d_in[11], d_in[12], srcF, WfcF, arr, flag);
  k_rnn<<<dim3(256), dim3(512), 0, stream>>>(
      srcF, WeG, WdG, WihEG, bEG, uDG, bDG, WfcF, hA, hB, d_out, flag, arr);
}